// Round 11
// baseline (258.186 us; speedup 1.0000x reference)
//
#include <hip/hip_runtime.h>
#include <hip/hip_bf16.h>

typedef __bf16 bf16;
typedef __attribute__((ext_vector_type(8))) __bf16 bf16x8;
typedef __attribute__((ext_vector_type(4))) float f32x4;

#define NBLK 256  // radix chunks == scanA block size (bucket-aligned scan)

// unpack 8 packed bf16 (uint4) -> two f32x4
__device__ inline void unpack8(uint4 r, f32x4& a, f32x4& b) {
  a.x = __uint_as_float(r.x << 16);
  a.y = __uint_as_float(r.x & 0xffff0000u);
  a.z = __uint_as_float(r.y << 16);
  a.w = __uint_as_float(r.y & 0xffff0000u);
  b.x = __uint_as_float(r.z << 16);
  b.y = __uint_as_float(r.z & 0xffff0000u);
  b.z = __uint_as_float(r.w << 16);
  b.w = __uint_as_float(r.w & 0xffff0000u);
}

// predicated 8-rows-per-wave slot load: slot q = lane>>3, 8 lanes cover a 128 B row
__device__ inline uint4 slot_load(const bf16* __restrict__ tab, const int* __restrict__ nbr,
                                  int base, int e, int q, int fo) {
  int idx = base + q;
  uint4 r = make_uint4(0u, 0u, 0u, 0u);
  if (idx < e) {
    int j = nbr[idx];
    r = *(const uint4*)(tab + j * 64 + fo);
  }
  return r;
}

// Fused setup: blocks [0,NBLK) histogram; [NBLK,NBLK+128) pack B1/B2; rest cvt x->xb.
__global__ __launch_bounds__(256) void setup_k(const float* __restrict__ x,
                                               const int* __restrict__ dst,
                                               const float* __restrict__ W1l,
                                               const float* __restrict__ W1r,
                                               const float* __restrict__ W2l,
                                               const float* __restrict__ W2r,
                                               bf16* __restrict__ xb,
                                               bf16* __restrict__ B1,
                                               bf16* __restrict__ B2,
                                               int* __restrict__ hist,
                                               int E, int nb, int N, int Np) {
  __shared__ int h[1024];
  int t = threadIdx.x;
  if (blockIdx.x < NBLK) {
    // per-chunk LDS histogram -> hist[bucket * NBLK + chunk]
    for (int i = t; i < nb; i += 256) h[i] = 0;
    __syncthreads();
    int chunk = (E + NBLK - 1) / NBLK;
    int s = blockIdx.x * chunk, e = min(E, s + chunk);
    for (int i = s + t; i < e; i += 256) atomicAdd(&h[dst[i] >> 7], 1);
    __syncthreads();
    for (int i = t; i < nb; i += 256) hist[(long)i * NBLK + blockIdx.x] = h[i];
  } else if (blockIdx.x < NBLK + 128) {
    int gid = (blockIdx.x - NBLK) * 256 + t;  // 0..32767
    if (gid < 16384) {
      int c = gid >> 7, k = gid & 127;
      float v = (k < 64) ? W1l[c * 64 + k] : W1r[c * 64 + (k - 64)];
      B1[gid] = (bf16)v;
    } else {
      int idx = gid - 16384;
      int n = idx >> 7, k = idx & 127;
      float v = (n < 64) ? W2l[n * 128 + k] : W2r[(n - 64) * 128 + k];
      B2[idx] = (bf16)v;
    }
  } else {
    int gid = (blockIdx.x - NBLK - 128) * 256 + t;  // one per 4 elems
    long base = (long)gid * 4;
    if (base >= (long)Np * 64) return;
    if (base < (long)N * 64) {
      f32x4 v = *(const f32x4*)(x + base);
      bf16 o[4] = {(bf16)v.x, (bf16)v.y, (bf16)v.z, (bf16)v.w};
      *(ulong1*)(xb + base) = *(ulong1*)o;
    } else {
      bf16 o[4] = {(bf16)0.0f, (bf16)0.0f, (bf16)0.0f, (bf16)0.0f};
      *(ulong1*)(xb + base) = *(ulong1*)o;
    }
  }
}

// scanA: one block per bucket; exclusive scan of the bucket's 256 chunk counts
// in place; bucket total -> bsum[bucket].
__global__ __launch_bounds__(256) void scanA_k(int* __restrict__ hist,
                                               int* __restrict__ bsum) {
  __shared__ int sd[256];
  int t = threadIdx.x;
  int idx = blockIdx.x * 256 + t;
  int v = hist[idx];
  sd[t] = v;
  __syncthreads();
#pragma unroll
  for (int off = 1; off < 256; off <<= 1) {
    int tv = (t >= off) ? sd[t - off] : 0;
    __syncthreads();
    if (t >= off) sd[t] += tv;
    __syncthreads();
  }
  hist[idx] = sd[t] - v;  // bucket-local exclusive prefix
  if (t == 255) bsum[blockIdx.x] = sd[255];
}

// scanB: single-block in-place exclusive scan of bsum (nb <= 1024).
// Afterwards bsum[b] = global start offset of bucket b.
__global__ __launch_bounds__(1024) void scanB_k(int* __restrict__ bsum, int nb) {
  __shared__ int sd[1024];
  int t = threadIdx.x;
  int v = (t < nb) ? bsum[t] : 0;
  sd[t] = v;
  __syncthreads();
#pragma unroll
  for (int off = 1; off < 1024; off <<= 1) {
    int tv = (t >= off) ? sd[t - off] : 0;
    __syncthreads();
    if (t >= off) sd[t] += tv;
    __syncthreads();
  }
  if (t < nb) bsum[t] = sd[t] - v;
}

// Pass 2: re-read chunk, LDS cursors = bsum[b] + hist[b][chunk], write packed
// records (src<<7 | local-dst) into bucket regions.
__global__ __launch_bounds__(512) void scat_k(const int* __restrict__ src,
                                              const int* __restrict__ dst,
                                              const int* __restrict__ hist,
                                              const int* __restrict__ bsum,
                                              unsigned* __restrict__ ebuf, int E, int nb) {
  __shared__ int cur[1024];
  for (int i = threadIdx.x; i < nb; i += 512)
    cur[i] = bsum[i] + hist[(long)i * NBLK + blockIdx.x];
  __syncthreads();
  int chunk = (E + NBLK - 1) / NBLK;
  int s = blockIdx.x * chunk, e = min(E, s + chunk);
  for (int i = s + threadIdx.x; i < e; i += 512) {
    int d = dst[i];
    int pos = atomicAdd(&cur[d >> 7], 1);
    ebuf[pos] = ((unsigned)src[i] << 7) | (unsigned)(d & 127);
  }
}

// per-bucket LDS counting sort -> node-ordered nbr + rowptr.
__global__ __launch_bounds__(256) void csr_k(const unsigned* __restrict__ ebuf,
                                             const int* __restrict__ bsum,
                                             int* __restrict__ rowptr,
                                             int* __restrict__ nbr, int nb, int Np, int E) {
  __shared__ int hcnt[128];
  __shared__ int hoff[128];
  int b = blockIdx.x, t = threadIdx.x;
  int s = bsum[b];
  int e = (b + 1 < nb) ? bsum[b + 1] : E;
  if (t < 128) hcnt[t] = 0;
  __syncthreads();
  for (int i = s + t; i < e; i += 256) atomicAdd(&hcnt[ebuf[i] & 127u], 1);
  __syncthreads();
  if (t < 128) hoff[t] = hcnt[t];
  __syncthreads();
#pragma unroll
  for (int off = 1; off < 128; off <<= 1) {
    int v = (t < 128 && t >= off) ? hoff[t - off] : 0;
    __syncthreads();
    if (t < 128 && t >= off) hoff[t] += v;
    __syncthreads();
  }
  if (t < 128) {
    int ex = hoff[t] - hcnt[t];  // exclusive scan
    rowptr[b * 128 + t] = s + ex;
    hcnt[t] = ex;  // becomes relative cursor
  }
  if (blockIdx.x == gridDim.x - 1 && t == 0) rowptr[Np] = E;
  __syncthreads();
  for (int i = s + t; i < e; i += 256) {
    unsigned r = ebuf[i];
    int pos = atomicAdd(&hcnt[r & 127u], 1);
    nbr[s + pos] = (int)(r >> 7);
  }
}

// ---- layer 1: wave per node; 8 lanes/row uint4 gathers, depth-2 pipeline ----
__global__ __launch_bounds__(256) void agg1_k(const bf16* __restrict__ xb,
                                              const int* __restrict__ rowptr,
                                              const int* __restrict__ nbr,
                                              bf16* __restrict__ A1, int Np) {
  int wave = threadIdx.x >> 6, lane = threadIdx.x & 63;
  int n = blockIdx.x * 4 + wave;
  if (n >= Np) return;
  int s = rowptr[n], e = rowptr[n + 1];
  int q = lane >> 3, f = lane & 7;
  int fo = f * 8;  // 8 features per lane (16 B)
  f32x4 sa = {0, 0, 0, 0}, sb = {0, 0, 0, 0};
  uint4 c0 = slot_load(xb, nbr, s, e, q, fo);
  uint4 c1 = slot_load(xb, nbr, s + 8, e, q, fo);
  int i = s + 16;
  for (; i < e; i += 16) {
    uint4 n0 = slot_load(xb, nbr, i, e, q, fo);
    uint4 n1 = slot_load(xb, nbr, i + 8, e, q, fo);
    f32x4 a, b;
    unpack8(c0, a, b); sa += a; sb += b;
    unpack8(c1, a, b); sa += a; sb += b;
    c0 = n0; c1 = n1;
  }
  {
    f32x4 a, b;
    unpack8(c0, a, b); sa += a; sb += b;
    unpack8(c1, a, b); sa += a; sb += b;
  }
  float v[8] = {sa.x, sa.y, sa.z, sa.w, sb.x, sb.y, sb.z, sb.w};
#pragma unroll
  for (int k = 0; k < 8; k++) {
    v[k] += __shfl_xor(v[k], 8);
    v[k] += __shfl_xor(v[k], 16);
    v[k] += __shfl_xor(v[k], 32);
  }
  float invd = 1.0f / fmaxf((float)(e - s), 1.0f);
  if (q == 0) {
    bf16x8 o = {(bf16)(v[0] * invd), (bf16)(v[1] * invd), (bf16)(v[2] * invd),
                (bf16)(v[3] * invd), (bf16)(v[4] * invd), (bf16)(v[5] * invd),
                (bf16)(v[6] * invd), (bf16)(v[7] * invd)};
    *(bf16x8*)(A1 + n * 128 + fo) = o;
  } else if (q == 1) {
    uint4 rv = *(const uint4*)(xb + n * 64 + fo);  // pads: xb==0
    *(uint4*)(A1 + n * 128 + 64 + fo) = rv;
  }
}

// ---- fused GEMM1+GEMM2, 64 rows/block (wave owns a 16-row m-tile) ----
// h = relu(A1*B1^T + b1l) stays in LDS; C2 = h*B2^T. Grid 2x vs 128-row
// version; LDS 17 KB -> ~6 resident blocks/CU for latency hiding.
__global__ __launch_bounds__(256) void gemm2x_k(const bf16* __restrict__ A,
                                                const bf16* __restrict__ B1,
                                                const bf16* __restrict__ B2,
                                                const float* __restrict__ b1l,
                                                bf16* __restrict__ Ct,
                                                bf16* __restrict__ Cu) {
  __shared__ bf16 hl[64][136];  // +8 pad: row stride 272 B -> bank advance 4/row
  int wave = threadIdx.x >> 6;
  int lane = threadIdx.x & 63;
  int row = lane & 15;
  int quad = lane >> 4;
  long mbase = (long)blockIdx.x * 64 + (long)wave * 16;
  int mloc = wave * 16;

  // ---- GEMM1 ----
  f32x4 acc[8] = {};
#pragma unroll
  for (int s = 0; s < 4; s++) {
    bf16x8 a0 = *(const bf16x8*)(A + (mbase + row) * 128 + s * 32 + quad * 8);
#pragma unroll
    for (int j = 0; j < 8; j++) {
      bf16x8 bf = *(const bf16x8*)(B1 + (long)(j * 16 + row) * 128 + s * 32 + quad * 8);
      acc[j] = __builtin_amdgcn_mfma_f32_16x16x32_bf16(a0, bf, acc[j], 0, 0, 0);
    }
  }
  // epilogue 1: bias + relu -> LDS (C/D layout: col=j*16+row, row=quad*4+i)
#pragma unroll
  for (int j = 0; j < 8; j++) {
    int col = j * 16 + row;
    float bv = b1l[col];
#pragma unroll
    for (int i = 0; i < 4; i++) {
      float v = acc[j][i] + bv;
      v = v > 0.0f ? v : 0.0f;
      hl[mloc + quad * 4 + i][col] = (bf16)v;
    }
  }
  __syncthreads();

  // ---- GEMM2 ----
  f32x4 acc2[8] = {};
#pragma unroll
  for (int s = 0; s < 4; s++) {
    bf16x8 a0 = *(const bf16x8*)(&hl[mloc + row][s * 32 + quad * 8]);
#pragma unroll
    for (int j = 0; j < 8; j++) {
      bf16x8 bf = *(const bf16x8*)(B2 + (long)(j * 16 + row) * 128 + s * 32 + quad * 8);
      acc2[j] = __builtin_amdgcn_mfma_f32_16x16x32_bf16(a0, bf, acc2[j], 0, 0, 0);
    }
  }
  // epilogue 2: split store cols 0..63 -> Ct, 64..127 -> Cu (ld 64 each)
#pragma unroll
  for (int j = 0; j < 8; j++) {
    int col = j * 16 + row;
#pragma unroll
    for (int i = 0; i < 4; i++) {
      float v = acc2[j][i];
      long mrow = mbase + quad * 4 + i;
      if (col < 64) Ct[mrow * 64 + col] = (bf16)v;
      else Cu[mrow * 64 + (col - 64)] = (bf16)v;
    }
  }
}

// ---- layer 2: wave per node; 8 lanes/row uint4 gathers; fused bias+root+out ----
__global__ __launch_bounds__(256) void agg2_k(const bf16* __restrict__ tmat,
                                              const bf16* __restrict__ umat,
                                              const int* __restrict__ rowptr,
                                              const int* __restrict__ nbr,
                                              const float* __restrict__ b2l,
                                              float* __restrict__ out, int N) {
  int wave = threadIdx.x >> 6, lane = threadIdx.x & 63;
  int n = blockIdx.x * 4 + wave;
  if (n >= N) return;
  int s = rowptr[n], e = rowptr[n + 1];
  int q = lane >> 3, f = lane & 7;
  int fo = f * 8;
  f32x4 sa = {0, 0, 0, 0}, sb = {0, 0, 0, 0};
  uint4 c0 = slot_load(tmat, nbr, s, e, q, fo);
  uint4 c1 = slot_load(tmat, nbr, s + 8, e, q, fo);
  int i = s + 16;
  for (; i < e; i += 16) {
    uint4 n0 = slot_load(tmat, nbr, i, e, q, fo);
    uint4 n1 = slot_load(tmat, nbr, i + 8, e, q, fo);
    f32x4 a, b;
    unpack8(c0, a, b); sa += a; sb += b;
    unpack8(c1, a, b); sa += a; sb += b;
    c0 = n0; c1 = n1;
  }
  {
    f32x4 a, b;
    unpack8(c0, a, b); sa += a; sb += b;
    unpack8(c1, a, b); sa += a; sb += b;
  }
  float v[8] = {sa.x, sa.y, sa.z, sa.w, sb.x, sb.y, sb.z, sb.w};
#pragma unroll
  for (int k = 0; k < 8; k++) {
    v[k] += __shfl_xor(v[k], 8);
    v[k] += __shfl_xor(v[k], 16);
    v[k] += __shfl_xor(v[k], 32);
  }
  if (q == 0) {
    float invd = 1.0f / fmaxf((float)(e - s), 1.0f);
    f32x4 b0 = *(const f32x4*)(b2l + fo);
    f32x4 b1 = *(const f32x4*)(b2l + fo + 4);
    f32x4 ua, ub;
    unpack8(*(const uint4*)(umat + n * 64 + fo), ua, ub);
    f32x4 o0, o1;
    o0.x = v[0] * invd + b0.x + ua.x;
    o0.y = v[1] * invd + b0.y + ua.y;
    o0.z = v[2] * invd + b0.z + ua.z;
    o0.w = v[3] * invd + b0.w + ua.w;
    o1.x = v[4] * invd + b1.x + ub.x;
    o1.y = v[5] * invd + b1.y + ub.y;
    o1.z = v[6] * invd + b1.z + ub.z;
    o1.w = v[7] * invd + b1.w + ub.w;
    *(f32x4*)(out + n * 64 + fo) = o0;
    *(f32x4*)(out + n * 64 + fo + 4) = o1;
  }
}

static inline size_t align256(size_t x) { return (x + 255) / 256 * 256; }

extern "C" void kernel_launch(void* const* d_in, const int* in_sizes, int n_in,
                              void* d_out, int out_size, void* d_ws, size_t ws_size,
                              hipStream_t stream) {
  const float* x = (const float*)d_in[0];
  const int* edge_index = (const int*)d_in[1];
  const float* W1l = (const float*)d_in[2];
  const float* b1l = (const float*)d_in[3];
  const float* W1r = (const float*)d_in[4];
  const float* W2l = (const float*)d_in[5];
  const float* b2l = (const float*)d_in[6];
  const float* W2r = (const float*)d_in[7];

  const int N = in_sizes[0] / 64;        // 100000
  const int E = in_sizes[1] / 2;         // 1200000
  const int Np = (N + 127) / 128 * 128;  // 100096
  const int nb = Np / 128;               // 782 buckets (<=1024 for scanB)
  const int M = nb * NBLK;               // hist elements (200192)

  const int* src = edge_index;
  const int* dst = edge_index + E;

  // ws layout (~75 MB; must not alias: gemm2x reads A1 while writing tmat/umat)
  char* ws = (char*)d_ws;
  size_t off = 0;
  int* hist = (int*)(ws + off);           off += align256((size_t)M * 4);
  int* bsum = (int*)(ws + off);           off += align256((size_t)nb * 4);
  int* rowptr = (int*)(ws + off);         off += align256((size_t)(Np + 1) * 4);
  unsigned* ebuf = (unsigned*)(ws + off); off += align256((size_t)E * 4);
  int* nbr = (int*)(ws + off);            off += align256((size_t)E * 4);
  bf16* xb = (bf16*)(ws + off);           off += align256((size_t)Np * 64 * 2);
  bf16* A1 = (bf16*)(ws + off);           off += align256((size_t)Np * 128 * 2);
  bf16* tmat = (bf16*)(ws + off);         off += align256((size_t)Np * 64 * 2);
  bf16* umat = (bf16*)(ws + off);         off += align256((size_t)Np * 64 * 2);
  bf16* B1 = (bf16*)(ws + off);           off += align256(128 * 128 * 2);
  bf16* B2 = (bf16*)(ws + off);           off += align256(128 * 128 * 2);
  float* out = (float*)d_out;

  const int cvtBlocks = (int)(((long)Np * 64 / 4 + 255) / 256);
  setup_k<<<NBLK + 128 + cvtBlocks, 256, 0, stream>>>(x, dst, W1l, W1r, W2l, W2r,
                                                      xb, B1, B2, hist, E, nb, N, Np);
  scanA_k<<<nb, 256, 0, stream>>>(hist, bsum);
  scanB_k<<<1, 1024, 0, stream>>>(bsum, nb);
  scat_k<<<NBLK, 512, 0, stream>>>(src, dst, hist, bsum, ebuf, E, nb);
  csr_k<<<nb, 256, 0, stream>>>(ebuf, bsum, rowptr, nbr, nb, Np, E);

  agg1_k<<<Np / 4, 256, 0, stream>>>(xb, rowptr, nbr, A1, Np);
  gemm2x_k<<<Np / 64, 256, 0, stream>>>(A1, B1, B2, b1l, tmat, umat);
  agg2_k<<<(N + 3) / 4, 256, 0, stream>>>(tmat, umat, rowptr, nbr, b2l, out, N);
}